// Round 9
// baseline (145.882 us; speedup 1.0000x reference)
//
#include <hip/hip_runtime.h>

#define BB 32
#define SS 2048
#define VV 516
#define NBS (BB * SS)      // 65536
#define NCHUNK 16
#define NPART 256          // comb block count

__device__ __forceinline__ float waveReduceSum(float v) {
    #pragma unroll
    for (int o = 32; o > 0; o >>= 1) v += __shfl_down(v, o, 64);
    return v;
}

// One block per (b, v-chunk), 512 threads (8 waves).  Single HBM sweep, NO
// LDS data staging: each thread keeps an 8-row x 4-col register tile.
//   - prefetch next sub-chunk into the alternate named register buffer
//     (loads stay in flight across both barriers: lgkmcnt-only waits)
//   - exp in place (capturing exact target logit x first)
//   - row sums: 8 shfl-tree reduces -> 8 floats/wave -> tiny LDS -> rcp
//   - score from registers: sum_v e, argmax of e*rcp (== softmax_S value)
// Two raw s_barriers per sub-chunk; no vmcnt drain anywhere in the loop.
__global__ __launch_bounds__(512, 4) void hl_tile(const float* __restrict__ x,
                                                  const int* __restrict__ target,
                                                  int* __restrict__ ctr,
                                                  float* __restrict__ pSum,
                                                  float* __restrict__ pBest,
                                                  int* __restrict__ pIdx,
                                                  float* __restrict__ xtArr) {
    __shared__ float ldsR[8][8];
    __shared__ float sRcp[8];

    if (blockIdx.x == 0 && threadIdx.x == 0) ctr[0] = 0;   // comb finalize ctr

    const int c = blockIdx.x & 15, b = blockIdx.x >> 4;
    const int v0 = 32 * c + (c > 12 ? c - 12 : 0);          // 12x32 + 4x33
    const int nv = (c >= 12) ? 33 : 32;
    const int tid = threadIdx.x, lane = tid & 63, wv = tid >> 6;
    const int s0 = tid << 2;
    const int bs = b * SS + s0;

    int4 tg4 = *(const int4*)(target + bs);
    int tg[4] = {tg4.x, tg4.y, tg4.z, tg4.w};

    float sum[4]  = {0.f, 0.f, 0.f, 0.f};
    float best[4] = {-1.f, -1.f, -1.f, -1.f};
    float xt[4]   = {0.f, 0.f, 0.f, 0.f};
    int   bi[4]   = {v0, v0, v0, v0};

    const float* xb = x + (size_t)(b * VV + v0) * SS + s0;

    float4 va[8], vb[8];
    #pragma unroll
    for (int r = 0; r < 8; ++r)                       // prologue: sub-chunk 0
        va[r] = *(const float4*)(xb + (size_t)r * SS);

#define TILE_BODY(CUR, NXT, KK)                                               \
    {                                                                         \
        if ((KK) + 1 < 4) {                                                   \
            _Pragma("unroll")                                                 \
            for (int r = 0; r < 8; ++r)                                       \
                NXT[r] = *(const float4*)(xb + (size_t)(((KK)+1)*8 + r) * SS);\
        }                                                                     \
        float rp[8];                                                          \
        _Pragma("unroll")                                                     \
        for (int r = 0; r < 8; ++r) {                                         \
            int vg = v0 + (KK)*8 + r;                                         \
            float4 xv = CUR[r];                                               \
            if (vg == tg[0]) xt[0] = xv.x;                                    \
            if (vg == tg[1]) xt[1] = xv.y;                                    \
            if (vg == tg[2]) xt[2] = xv.z;                                    \
            if (vg == tg[3]) xt[3] = xv.w;                                    \
            float4 e;                                                         \
            e.x = __expf(xv.x); e.y = __expf(xv.y);                           \
            e.z = __expf(xv.z); e.w = __expf(xv.w);                           \
            CUR[r] = e;                                                       \
            rp[r] = (e.x + e.y) + (e.z + e.w);                                \
        }                                                                     \
        _Pragma("unroll")                                                     \
        for (int r = 0; r < 8; ++r) rp[r] = waveReduceSum(rp[r]);             \
        if (lane == 0) {                                                      \
            _Pragma("unroll")                                                 \
            for (int r = 0; r < 8; ++r) ldsR[wv][r] = rp[r];                  \
        }                                                                     \
        asm volatile("s_waitcnt lgkmcnt(0)" ::: "memory");                    \
        __builtin_amdgcn_s_barrier();                                         \
        if (tid < 8) {                                                        \
            float s = 0.f;                                                    \
            _Pragma("unroll")                                                 \
            for (int w = 0; w < 8; ++w) s += ldsR[w][tid];                    \
            sRcp[tid] = 1.f / s;                                              \
        }                                                                     \
        asm volatile("s_waitcnt lgkmcnt(0)" ::: "memory");                    \
        __builtin_amdgcn_s_barrier();                                         \
        _Pragma("unroll")                                                     \
        for (int r = 0; r < 8; ++r) {                                         \
            float rc = sRcp[r];                                               \
            int vg = v0 + (KK)*8 + r;                                         \
            float4 e = CUR[r];                                                \
            sum[0] += e.x; sum[1] += e.y; sum[2] += e.z; sum[3] += e.w;       \
            float c0 = e.x*rc, c1 = e.y*rc, c2 = e.z*rc, c3 = e.w*rc;         \
            if (c0 > best[0]) { best[0] = c0; bi[0] = vg; }                   \
            if (c1 > best[1]) { best[1] = c1; bi[1] = vg; }                   \
            if (c2 > best[2]) { best[2] = c2; bi[2] = vg; }                   \
            if (c3 > best[3]) { best[3] = c3; bi[3] = vg; }                   \
        }                                                                     \
    }

    TILE_BODY(va, vb, 0)
    TILE_BODY(vb, va, 1)
    TILE_BODY(va, vb, 2)
    TILE_BODY(vb, va, 3)
#undef TILE_BODY

    if (nv == 33) {                                   // tail: one extra row
        int vg = v0 + 32;
        float4 xv = *(const float4*)(xb + (size_t)32 * SS);
        if (vg == tg[0]) xt[0] = xv.x;
        if (vg == tg[1]) xt[1] = xv.y;
        if (vg == tg[2]) xt[2] = xv.z;
        if (vg == tg[3]) xt[3] = xv.w;
        float4 e;
        e.x = __expf(xv.x); e.y = __expf(xv.y);
        e.z = __expf(xv.z); e.w = __expf(xv.w);
        float rp = waveReduceSum((e.x + e.y) + (e.z + e.w));
        if (lane == 0) ldsR[wv][0] = rp;
        asm volatile("s_waitcnt lgkmcnt(0)" ::: "memory");
        __builtin_amdgcn_s_barrier();
        if (tid == 0) {
            float s = 0.f;
            #pragma unroll
            for (int w = 0; w < 8; ++w) s += ldsR[w][0];
            sRcp[0] = 1.f / s;
        }
        asm volatile("s_waitcnt lgkmcnt(0)" ::: "memory");
        __builtin_amdgcn_s_barrier();
        float rc = sRcp[0];
        sum[0] += e.x; sum[1] += e.y; sum[2] += e.z; sum[3] += e.w;
        float c0 = e.x*rc, c1 = e.y*rc, c2 = e.z*rc, c3 = e.w*rc;
        if (c0 > best[0]) { best[0] = c0; bi[0] = vg; }
        if (c1 > best[1]) { best[1] = c1; bi[1] = vg; }
        if (c2 > best[2]) { best[2] = c2; bi[2] = vg; }
        if (c3 > best[3]) { best[3] = c3; bi[3] = vg; }
    }

    // ---- write per-chunk partials ----
    int o = c * NBS + bs;
    *(float4*)(pSum + o)  = make_float4(sum[0], sum[1], sum[2], sum[3]);
    *(float4*)(pBest + o) = make_float4(best[0], best[1], best[2], best[3]);
    *(int4*)(pIdx + o)    = make_int4(bi[0], bi[1], bi[2], bi[3]);
    int v1 = v0 + nv;
    #pragma unroll
    for (int i = 0; i < 4; ++i)
        if (tg[i] >= v0 && tg[i] < v1) xtArr[bs + i] = xt[i];
}

// Merge chunk partials per (b,s); nll + penalty mask; block partial sums;
// last block folds the 256 partials into the scalar output.  (R3-proven.)
__global__ __launch_bounds__(256) void hl_comb(const int* __restrict__ target,
                                               const int* __restrict__ ttype,
                                               const float* __restrict__ tval,
                                               const float* __restrict__ coeff,
                                               const float* __restrict__ harm,
                                               const float* __restrict__ pSum,
                                               const float* __restrict__ pBest,
                                               const int* __restrict__ pIdx,
                                               const float* __restrict__ xtArr,
                                               float* __restrict__ pNll,
                                               float* __restrict__ pMask,
                                               int* __restrict__ counter,
                                               float* __restrict__ outv) {
    __shared__ float lds[8];
    __shared__ bool isLast;
    int idx = blockIdx.x * 256 + threadIdx.x;            // (b,s) flat

    float sum = 0.f, best = -1e30f;
    int bestIdx = 0;
    #pragma unroll
    for (int c = 0; c < NCHUNK; ++c) {                   // ascending: first-idx ties
        int o = c * NBS + idx;
        sum += pSum[o];
        float sc = pBest[o];
        int ii = pIdx[o];
        if (sc > best) { best = sc; bestIdx = ii; }
    }
    int tgt = target[idx];
    float nll = __logf(sum) - xtArr[idx];

    int pt = ttype[bestIdx], tt = ttype[tgt];
    float pv = tval[bestIdx], tv = tval[tgt];
    float d = fabsf(pv - tv);
    float pw = (d == 7.f) ? harm[0] : (d == 5.f) ? harm[1] : (d == 3.f) ? harm[2]
             : (d == 4.f) ? harm[3] : (d == 1.f) ? harm[4] : (d == 2.f) ? harm[5]
             : harm[6];
    float w = (pt == 0) ? pw
            : (pt == 1) ? coeff[1] * d * (1.f / 160.f)
            : (pt == 2) ? coeff[2] * d * (1.f / 100.f)
            :             coeff[3] * d * (1.f / 128.f);
    float mask = (pt != tt) ? coeff[0] : w;

    int lane = threadIdx.x & 63, wvv = threadIdx.x >> 6;
    float rn = waveReduceSum(nll);
    if (lane == 0) lds[wvv] = rn;
    __syncthreads();
    float totN = (threadIdx.x == 0) ? lds[0] + lds[1] + lds[2] + lds[3] : 0.f;
    __syncthreads();
    float rm = waveReduceSum(mask);
    if (lane == 0) lds[wvv] = rm;
    __syncthreads();
    if (threadIdx.x == 0) {
        pNll[blockIdx.x]  = totN;
        pMask[blockIdx.x] = lds[0] + lds[1] + lds[2] + lds[3];
        __threadfence();
        unsigned old = atomicAdd((unsigned*)counter, 1u);
        isLast = (old == NPART - 1);
    }
    __syncthreads();
    if (isLast) {
        __threadfence();
        int t = threadIdx.x;
        float n = waveReduceSum(pNll[t]);
        float m = waveReduceSum(pMask[t]);
        if (lane == 0) { lds[wvv] = n; lds[4 + wvv] = m; }
        __syncthreads();
        if (t == 0) {
            float tn = lds[0] + lds[1] + lds[2] + lds[3];
            float tm = lds[4] + lds[5] + lds[6] + lds[7];
            const float inv = 1.f / (float)NBS;
            outv[0] = (tn * inv) * (1.f + tm * inv);
        }
    }
}

extern "C" void kernel_launch(void* const* d_in, const int* in_sizes, int n_in,
                              void* d_out, int out_size, void* d_ws, size_t ws_size,
                              hipStream_t stream) {
    const float* x      = (const float*)d_in[0];
    const int*   target = (const int*)d_in[1];
    const int*   ttype  = (const int*)d_in[2];
    const float* tval   = (const float*)d_in[3];
    const float* coeff  = (const float*)d_in[4];
    const float* harm   = (const float*)d_in[5];

    float* ws    = (float*)d_ws;
    int*   ctr   = (int*)ws;                     // 4 ints
    float* pNll  = ws + 4;                       // 256
    float* pMask = pNll + NPART;                 // 256
    float* xtArr = pMask + NPART;                // 65536 (offset 516 -> 16B-aligned)
    float* pSum  = xtArr + NBS;                  // 16*65536
    float* pBest = pSum + (size_t)NCHUNK * NBS;  // 16*65536
    int*   pIdx  = (int*)(pBest + (size_t)NCHUNK * NBS);

    hl_tile<<<BB * NCHUNK, 512, 0, stream>>>(x, target, ctr, pSum, pBest,
                                             pIdx, xtArr);
    hl_comb<<<NBS / 256, 256, 0, stream>>>(target, ttype, tval, coeff, harm,
                                           pSum, pBest, pIdx, xtArr,
                                           pNll, pMask, ctr, (float*)d_out);
}

// Round 10
// 68.209 us; speedup vs baseline: 2.1388x; 2.1388x over previous
//
#include <hip/hip_runtime.h>

#define BB 32
#define SS 2048
#define VV 516
#define NBS (BB * SS)      // 65536
#define NCHUNK 16
#define NPART 256          // comb block count

__device__ __forceinline__ float waveReduceSum(float v) {
    #pragma unroll
    for (int o = 32; o > 0; o >>= 1) v += __shfl_down(v, o, 64);
    return v;
}

// One block per (b, v-chunk), 512 threads (8 waves).  Single HBM sweep, NO
// LDS data staging: each thread keeps an 8-row x 4-col register tile.
//   - prefetch next sub-chunk into the alternate named register buffer
//     (loads stay in flight across both barriers: lgkmcnt-only waits)
//   - exp in place (capturing exact target logit x first)
//   - row sums: 8 shfl-tree reduces -> 8 floats/wave -> tiny LDS -> rcp
//   - score from registers: sum_v e, argmax of e*rcp (== softmax_S value)
// Two raw s_barriers per sub-chunk; no vmcnt drain anywhere in the loop.
// __launch_bounds__(512, 2): R8/R9 used (512,4) which capped the allocator
// at 64 VGPRs and spilled the register tile to scratch (229 MB of spill
// traffic).  (512,2) allows ~128 VGPRs -> the ~110-reg tile stays resident,
// still 2 blocks/CU (16 waves/CU).
__global__ __launch_bounds__(512, 2) void hl_tile(const float* __restrict__ x,
                                                  const int* __restrict__ target,
                                                  int* __restrict__ ctr,
                                                  float* __restrict__ pSum,
                                                  float* __restrict__ pBest,
                                                  int* __restrict__ pIdx,
                                                  float* __restrict__ xtArr) {
    __shared__ float ldsR[8][8];
    __shared__ float sRcp[8];

    if (blockIdx.x == 0 && threadIdx.x == 0) ctr[0] = 0;   // comb finalize ctr

    const int c = blockIdx.x & 15, b = blockIdx.x >> 4;
    const int v0 = 32 * c + (c > 12 ? c - 12 : 0);          // 12x32 + 4x33
    const int nv = (c >= 12) ? 33 : 32;
    const int tid = threadIdx.x, lane = tid & 63, wv = tid >> 6;
    const int s0 = tid << 2;
    const int bs = b * SS + s0;

    int4 tg4 = *(const int4*)(target + bs);
    int tg[4] = {tg4.x, tg4.y, tg4.z, tg4.w};

    float sum[4]  = {0.f, 0.f, 0.f, 0.f};
    float best[4] = {-1.f, -1.f, -1.f, -1.f};
    float xt[4]   = {0.f, 0.f, 0.f, 0.f};
    int   bi[4]   = {v0, v0, v0, v0};

    const float* xb = x + (size_t)(b * VV + v0) * SS + s0;

    float4 va[8], vb[8];
    #pragma unroll
    for (int r = 0; r < 8; ++r)                       // prologue: sub-chunk 0
        va[r] = *(const float4*)(xb + (size_t)r * SS);

#define TILE_BODY(CUR, NXT, KK)                                               \
    {                                                                         \
        if ((KK) + 1 < 4) {                                                   \
            _Pragma("unroll")                                                 \
            for (int r = 0; r < 8; ++r)                                       \
                NXT[r] = *(const float4*)(xb + (size_t)(((KK)+1)*8 + r) * SS);\
        }                                                                     \
        float rp[8];                                                          \
        _Pragma("unroll")                                                     \
        for (int r = 0; r < 8; ++r) {                                         \
            int vg = v0 + (KK)*8 + r;                                         \
            float4 xv = CUR[r];                                               \
            if (vg == tg[0]) xt[0] = xv.x;                                    \
            if (vg == tg[1]) xt[1] = xv.y;                                    \
            if (vg == tg[2]) xt[2] = xv.z;                                    \
            if (vg == tg[3]) xt[3] = xv.w;                                    \
            float4 e;                                                         \
            e.x = __expf(xv.x); e.y = __expf(xv.y);                           \
            e.z = __expf(xv.z); e.w = __expf(xv.w);                           \
            CUR[r] = e;                                                       \
            rp[r] = (e.x + e.y) + (e.z + e.w);                                \
        }                                                                     \
        _Pragma("unroll")                                                     \
        for (int r = 0; r < 8; ++r) rp[r] = waveReduceSum(rp[r]);             \
        if (lane == 0) {                                                      \
            _Pragma("unroll")                                                 \
            for (int r = 0; r < 8; ++r) ldsR[wv][r] = rp[r];                  \
        }                                                                     \
        asm volatile("s_waitcnt lgkmcnt(0)" ::: "memory");                    \
        __builtin_amdgcn_s_barrier();                                         \
        if (tid < 8) {                                                        \
            float s = 0.f;                                                    \
            _Pragma("unroll")                                                 \
            for (int w = 0; w < 8; ++w) s += ldsR[w][tid];                    \
            sRcp[tid] = 1.f / s;                                              \
        }                                                                     \
        asm volatile("s_waitcnt lgkmcnt(0)" ::: "memory");                    \
        __builtin_amdgcn_s_barrier();                                         \
        _Pragma("unroll")                                                     \
        for (int r = 0; r < 8; ++r) {                                         \
            float rc = sRcp[r];                                               \
            int vg = v0 + (KK)*8 + r;                                         \
            float4 e = CUR[r];                                                \
            sum[0] += e.x; sum[1] += e.y; sum[2] += e.z; sum[3] += e.w;       \
            float c0 = e.x*rc, c1 = e.y*rc, c2 = e.z*rc, c3 = e.w*rc;         \
            if (c0 > best[0]) { best[0] = c0; bi[0] = vg; }                   \
            if (c1 > best[1]) { best[1] = c1; bi[1] = vg; }                   \
            if (c2 > best[2]) { best[2] = c2; bi[2] = vg; }                   \
            if (c3 > best[3]) { best[3] = c3; bi[3] = vg; }                   \
        }                                                                     \
    }

    TILE_BODY(va, vb, 0)
    TILE_BODY(vb, va, 1)
    TILE_BODY(va, vb, 2)
    TILE_BODY(vb, va, 3)
#undef TILE_BODY

    if (nv == 33) {                                   // tail: one extra row
        int vg = v0 + 32;
        float4 xv = *(const float4*)(xb + (size_t)32 * SS);
        if (vg == tg[0]) xt[0] = xv.x;
        if (vg == tg[1]) xt[1] = xv.y;
        if (vg == tg[2]) xt[2] = xv.z;
        if (vg == tg[3]) xt[3] = xv.w;
        float4 e;
        e.x = __expf(xv.x); e.y = __expf(xv.y);
        e.z = __expf(xv.z); e.w = __expf(xv.w);
        float rp = waveReduceSum((e.x + e.y) + (e.z + e.w));
        if (lane == 0) ldsR[wv][0] = rp;
        asm volatile("s_waitcnt lgkmcnt(0)" ::: "memory");
        __builtin_amdgcn_s_barrier();
        if (tid == 0) {
            float s = 0.f;
            #pragma unroll
            for (int w = 0; w < 8; ++w) s += ldsR[w][0];
            sRcp[0] = 1.f / s;
        }
        asm volatile("s_waitcnt lgkmcnt(0)" ::: "memory");
        __builtin_amdgcn_s_barrier();
        float rc = sRcp[0];
        sum[0] += e.x; sum[1] += e.y; sum[2] += e.z; sum[3] += e.w;
        float c0 = e.x*rc, c1 = e.y*rc, c2 = e.z*rc, c3 = e.w*rc;
        if (c0 > best[0]) { best[0] = c0; bi[0] = vg; }
        if (c1 > best[1]) { best[1] = c1; bi[1] = vg; }
        if (c2 > best[2]) { best[2] = c2; bi[2] = vg; }
        if (c3 > best[3]) { best[3] = c3; bi[3] = vg; }
    }

    // ---- write per-chunk partials ----
    int o = c * NBS + bs;
    *(float4*)(pSum + o)  = make_float4(sum[0], sum[1], sum[2], sum[3]);
    *(float4*)(pBest + o) = make_float4(best[0], best[1], best[2], best[3]);
    *(int4*)(pIdx + o)    = make_int4(bi[0], bi[1], bi[2], bi[3]);
    int v1 = v0 + nv;
    #pragma unroll
    for (int i = 0; i < 4; ++i)
        if (tg[i] >= v0 && tg[i] < v1) xtArr[bs + i] = xt[i];
}

// Merge chunk partials per (b,s); nll + penalty mask; block partial sums;
// last block folds the 256 partials into the scalar output.  (R3-proven.)
__global__ __launch_bounds__(256) void hl_comb(const int* __restrict__ target,
                                               const int* __restrict__ ttype,
                                               const float* __restrict__ tval,
                                               const float* __restrict__ coeff,
                                               const float* __restrict__ harm,
                                               const float* __restrict__ pSum,
                                               const float* __restrict__ pBest,
                                               const int* __restrict__ pIdx,
                                               const float* __restrict__ xtArr,
                                               float* __restrict__ pNll,
                                               float* __restrict__ pMask,
                                               int* __restrict__ counter,
                                               float* __restrict__ outv) {
    __shared__ float lds[8];
    __shared__ bool isLast;
    int idx = blockIdx.x * 256 + threadIdx.x;            // (b,s) flat

    float sum = 0.f, best = -1e30f;
    int bestIdx = 0;
    #pragma unroll
    for (int c = 0; c < NCHUNK; ++c) {                   // ascending: first-idx ties
        int o = c * NBS + idx;
        sum += pSum[o];
        float sc = pBest[o];
        int ii = pIdx[o];
        if (sc > best) { best = sc; bestIdx = ii; }
    }
    int tgt = target[idx];
    float nll = __logf(sum) - xtArr[idx];

    int pt = ttype[bestIdx], tt = ttype[tgt];
    float pv = tval[bestIdx], tv = tval[tgt];
    float d = fabsf(pv - tv);
    float pw = (d == 7.f) ? harm[0] : (d == 5.f) ? harm[1] : (d == 3.f) ? harm[2]
             : (d == 4.f) ? harm[3] : (d == 1.f) ? harm[4] : (d == 2.f) ? harm[5]
             : harm[6];
    float w = (pt == 0) ? pw
            : (pt == 1) ? coeff[1] * d * (1.f / 160.f)
            : (pt == 2) ? coeff[2] * d * (1.f / 100.f)
            :             coeff[3] * d * (1.f / 128.f);
    float mask = (pt != tt) ? coeff[0] : w;

    int lane = threadIdx.x & 63, wvv = threadIdx.x >> 6;
    float rn = waveReduceSum(nll);
    if (lane == 0) lds[wvv] = rn;
    __syncthreads();
    float totN = (threadIdx.x == 0) ? lds[0] + lds[1] + lds[2] + lds[3] : 0.f;
    __syncthreads();
    float rm = waveReduceSum(mask);
    if (lane == 0) lds[wvv] = rm;
    __syncthreads();
    if (threadIdx.x == 0) {
        pNll[blockIdx.x]  = totN;
        pMask[blockIdx.x] = lds[0] + lds[1] + lds[2] + lds[3];
        __threadfence();
        unsigned old = atomicAdd((unsigned*)counter, 1u);
        isLast = (old == NPART - 1);
    }
    __syncthreads();
    if (isLast) {
        __threadfence();
        int t = threadIdx.x;
        float n = waveReduceSum(pNll[t]);
        float m = waveReduceSum(pMask[t]);
        if (lane == 0) { lds[wvv] = n; lds[4 + wvv] = m; }
        __syncthreads();
        if (t == 0) {
            float tn = lds[0] + lds[1] + lds[2] + lds[3];
            float tm = lds[4] + lds[5] + lds[6] + lds[7];
            const float inv = 1.f / (float)NBS;
            outv[0] = (tn * inv) * (1.f + tm * inv);
        }
    }
}

extern "C" void kernel_launch(void* const* d_in, const int* in_sizes, int n_in,
                              void* d_out, int out_size, void* d_ws, size_t ws_size,
                              hipStream_t stream) {
    const float* x      = (const float*)d_in[0];
    const int*   target = (const int*)d_in[1];
    const int*   ttype  = (const int*)d_in[2];
    const float* tval   = (const float*)d_in[3];
    const float* coeff  = (const float*)d_in[4];
    const float* harm   = (const float*)d_in[5];

    float* ws    = (float*)d_ws;
    int*   ctr   = (int*)ws;                     // 4 ints
    float* pNll  = ws + 4;                       // 256
    float* pMask = pNll + NPART;                 // 256
    float* xtArr = pMask + NPART;                // 65536 (offset 516 -> 16B-aligned)
    float* pSum  = xtArr + NBS;                  // 16*65536
    float* pBest = pSum + (size_t)NCHUNK * NBS;  // 16*65536
    int*   pIdx  = (int*)(pBest + (size_t)NCHUNK * NBS);

    hl_tile<<<BB * NCHUNK, 512, 0, stream>>>(x, target, ctr, pSum, pBest,
                                             pIdx, xtArr);
    hl_comb<<<NBS / 256, 256, 0, stream>>>(target, ttype, tval, coeff, harm,
                                           pSum, pBest, pIdx, xtArr,
                                           pNll, pMask, ctr, (float*)d_out);
}

// Round 11
// 52.915 us; speedup vs baseline: 2.7569x; 1.2890x over previous
//
#include <hip/hip_runtime.h>
#include <hip/hip_fp16.h>

#define BB 32
#define SS 2048
#define VV 516
#define NBS (BB * SS)      // 65536
#define NCHUNK 16
#define NPART 256          // comb block count

struct alignas(8) h4 { __half2 a, b; };

__device__ __forceinline__ float waveReduceSum(float v) {
    #pragma unroll
    for (int o = 32; o > 0; o >>= 1) v += __shfl_down(v, o, 64);
    return v;
}

// One block per (b, v-chunk), 512 threads (8 waves).  Single HBM sweep.
// TWO WAVES CO-OWN EACH ROW (half-row per wave) -> per-thread prefetch
// buffer is only 4 float4 (16 regs); double-buffered = 32 regs total, so the
// whole kernel fits ~70-90 VGPRs and CANNOT spill (R8/R9/R10's 64-reg tiles
// all spilled 66-150 MB of scratch traffic).
// Per 4-row sub-chunk k (kb = k&1):
//   1. issue prefetch(k+1) into the alternate named reg buffer
//   2. finish(k): e=exp(cur) -> fp16 pack -> ldsX[kb] + half-row 6-shfl sum
//      -> ldsH[kb][row][half]
//   3. lgkmcnt(0); raw s_barrier  (global prefetch NOT drained)
//   4. phase2(k): 4x h4 LDS reads + 8 broadcast ldsH reads; accumulate
//      sum_v e and argmax of e*rcp(rowsum) (== softmax_S value); gather
//      target logit as log(e) from LDS.
// Buffer parity: ldsX[kb] is rewritten by finish(k+2), which is after
// barrier(k+1), which is after every wave's phase2(k) -> race-free with ONE
// barrier per sub-chunk.
__global__ __launch_bounds__(512, 2) void hl_tile(const float* __restrict__ x,
                                                  const int* __restrict__ target,
                                                  int* __restrict__ ctr,
                                                  float* __restrict__ pSum,
                                                  float* __restrict__ pBest,
                                                  int* __restrict__ pIdx,
                                                  float* __restrict__ xtArr) {
    __shared__ __half ldsX[2][4][2048];   // 32 KB: 2 x 4 staged rows of exp(x)
    __shared__ float  ldsH[2][4][2];      // half-row sums

    if (blockIdx.x == 0 && threadIdx.x == 0) ctr[0] = 0;   // comb finalize ctr

    const int c = blockIdx.x & 15, b = blockIdx.x >> 4;
    const int v0 = 32 * c + (c > 12 ? c - 12 : 0);          // 12x32 + 4x33
    const int nv = (c >= 12) ? 33 : 32;
    const int tid = threadIdx.x, lane = tid & 63, wv = tid >> 6;
    const int row4 = wv >> 1;            // local row in sub-chunk (0..3)
    const int half = wv & 1;             // which half of the row
    const int colbase = half * 1024 + lane * 4;
    const int s0 = tid << 2;             // owned columns for accumulation
    const int bs = b * SS + s0;

    int4 tg4 = *(const int4*)(target + bs);
    int tg[4] = {tg4.x, tg4.y, tg4.z, tg4.w};

    float sum[4]  = {0.f, 0.f, 0.f, 0.f};
    float best[4] = {-1.f, -1.f, -1.f, -1.f};
    float xt[4]   = {0.f, 0.f, 0.f, 0.f};
    int   bi[4]   = {v0, v0, v0, v0};

    const float* xb = x + (size_t)(b * VV + v0) * SS;

    float4 vbA[4], vbB[4];
    {   // prologue: prefetch sub-chunk 0 (rows 0-3, half-rows)
        const float* rowp = xb + (size_t)row4 * SS + colbase;
        #pragma unroll
        for (int j = 0; j < 4; ++j)
            vbA[j] = *(const float4*)(rowp + j * 256);
    }

#define TILE_BODY(CUR, NXT, KK)                                               \
    {                                                                         \
        if ((KK) + 1 < 8) {                                                   \
            const float* rowp = xb + (size_t)(((KK)+1)*4 + row4) * SS + colbase;\
            _Pragma("unroll")                                                 \
            for (int j = 0; j < 4; ++j)                                       \
                NXT[j] = *(const float4*)(rowp + j * 256);                    \
        } else if (nv == 33 && wv < 2) {   /* prefetch tail row 32 */         \
            const float* rowp = xb + (size_t)32 * SS + colbase;               \
            _Pragma("unroll")                                                 \
            for (int j = 0; j < 4; ++j)                                       \
                NXT[j] = *(const float4*)(rowp + j * 256);                    \
        }                                                                     \
        {   /* finish(KK) */                                                  \
            float a0 = 0.f, a1 = 0.f, a2 = 0.f, a3 = 0.f;                     \
            __half* dst = &ldsX[(KK)&1][row4][colbase];                       \
            _Pragma("unroll")                                                 \
            for (int j = 0; j < 4; ++j) {                                     \
                float ex = __expf(CUR[j].x), ey = __expf(CUR[j].y);           \
                float ez = __expf(CUR[j].z), ew = __expf(CUR[j].w);           \
                h4 h;                                                         \
                h.a = __halves2half2(__float2half_rn(ex), __float2half_rn(ey));\
                h.b = __halves2half2(__float2half_rn(ez), __float2half_rn(ew));\
                *(h4*)(dst + j * 256) = h;                                    \
                a0 += ex; a1 += ey; a2 += ez; a3 += ew;                       \
            }                                                                 \
            float rs = waveReduceSum((a0 + a1) + (a2 + a3));                  \
            if (lane == 0) ldsH[(KK)&1][row4][half] = rs;                     \
        }                                                                     \
        asm volatile("s_waitcnt lgkmcnt(0)" ::: "memory");                    \
        __builtin_amdgcn_s_barrier();                                         \
        {   /* phase2(KK) */                                                  \
            h4 hv0 = *(const h4*)&ldsX[(KK)&1][0][s0];                        \
            h4 hv1 = *(const h4*)&ldsX[(KK)&1][1][s0];                        \
            h4 hv2 = *(const h4*)&ldsX[(KK)&1][2][s0];                        \
            h4 hv3 = *(const h4*)&ldsX[(KK)&1][3][s0];                        \
            float sr0 = ldsH[(KK)&1][0][0] + ldsH[(KK)&1][0][1];              \
            float sr1 = ldsH[(KK)&1][1][0] + ldsH[(KK)&1][1][1];              \
            float sr2 = ldsH[(KK)&1][2][0] + ldsH[(KK)&1][2][1];              \
            float sr3 = ldsH[(KK)&1][3][0] + ldsH[(KK)&1][3][1];              \
            ACC_ROW(hv0, sr0, v0 + (KK)*4 + 0)                                \
            ACC_ROW(hv1, sr1, v0 + (KK)*4 + 1)                                \
            ACC_ROW(hv2, sr2, v0 + (KK)*4 + 2)                                \
            ACC_ROW(hv3, sr3, v0 + (KK)*4 + 3)                                \
            _Pragma("unroll")                                                 \
            for (int i = 0; i < 4; ++i) {                                     \
                int lr = tg[i] - (v0 + (KK)*4);                               \
                if (lr >= 0 && lr < 4)                                        \
                    xt[i] = __logf(__half2float(ldsX[(KK)&1][lr][s0 + i]));   \
            }                                                                 \
        }                                                                     \
    }

#define ACC_ROW(HV, SR, VG)                                                   \
    {                                                                         \
        float rc = 1.f / (SR);                                                \
        int vg = (VG);                                                        \
        float e0 = __low2float((HV).a), e1 = __high2float((HV).a);            \
        float e2 = __low2float((HV).b), e3 = __high2float((HV).b);            \
        sum[0] += e0; sum[1] += e1; sum[2] += e2; sum[3] += e3;               \
        float c0 = e0*rc, c1 = e1*rc, c2 = e2*rc, c3 = e3*rc;                 \
        if (c0 > best[0]) { best[0] = c0; bi[0] = vg; }                       \
        if (c1 > best[1]) { best[1] = c1; bi[1] = vg; }                       \
        if (c2 > best[2]) { best[2] = c2; bi[2] = vg; }                       \
        if (c3 > best[3]) { best[3] = c3; bi[3] = vg; }                       \
    }

    TILE_BODY(vbA, vbB, 0)
    TILE_BODY(vbB, vbA, 1)
    TILE_BODY(vbA, vbB, 2)
    TILE_BODY(vbB, vbA, 3)
    TILE_BODY(vbA, vbB, 4)
    TILE_BODY(vbB, vbA, 5)
    TILE_BODY(vbA, vbB, 6)
    TILE_BODY(vbB, vbA, 7)
#undef TILE_BODY

    if (nv == 33) {   // tail row 32, prefetched into vbA by body(7)
        if (wv < 2) { // row4 == 0, half = wv&1
            float a0 = 0.f, a1 = 0.f, a2 = 0.f, a3 = 0.f;
            __half* dst = &ldsX[0][0][colbase];
            #pragma unroll
            for (int j = 0; j < 4; ++j) {
                float ex = __expf(vbA[j].x), ey = __expf(vbA[j].y);
                float ez = __expf(vbA[j].z), ew = __expf(vbA[j].w);
                h4 h;
                h.a = __halves2half2(__float2half_rn(ex), __float2half_rn(ey));
                h.b = __halves2half2(__float2half_rn(ez), __float2half_rn(ew));
                *(h4*)(dst + j * 256) = h;
                a0 += ex; a1 += ey; a2 += ez; a3 += ew;
            }
            float rs = waveReduceSum((a0 + a1) + (a2 + a3));
            if (lane == 0) ldsH[0][0][half] = rs;
        }
        asm volatile("s_waitcnt lgkmcnt(0)" ::: "memory");
        __builtin_amdgcn_s_barrier();
        h4 hv = *(const h4*)&ldsX[0][0][s0];
        float sr = ldsH[0][0][0] + ldsH[0][0][1];
        ACC_ROW(hv, sr, v0 + 32)
        #pragma unroll
        for (int i = 0; i < 4; ++i)
            if (tg[i] == v0 + 32)
                xt[i] = __logf(__half2float(ldsX[0][0][s0 + i]));
    }
#undef ACC_ROW

    // ---- write per-chunk partials ----
    int o = c * NBS + bs;
    *(float4*)(pSum + o)  = make_float4(sum[0], sum[1], sum[2], sum[3]);
    *(float4*)(pBest + o) = make_float4(best[0], best[1], best[2], best[3]);
    *(int4*)(pIdx + o)    = make_int4(bi[0], bi[1], bi[2], bi[3]);
    int v1 = v0 + nv;
    #pragma unroll
    for (int i = 0; i < 4; ++i)
        if (tg[i] >= v0 && tg[i] < v1) xtArr[bs + i] = xt[i];
}

// Merge chunk partials per (b,s); nll + penalty mask; block partial sums;
// last block folds the 256 partials into the scalar output.  (R3-proven.)
__global__ __launch_bounds__(256) void hl_comb(const int* __restrict__ target,
                                               const int* __restrict__ ttype,
                                               const float* __restrict__ tval,
                                               const float* __restrict__ coeff,
                                               const float* __restrict__ harm,
                                               const float* __restrict__ pSum,
                                               const float* __restrict__ pBest,
                                               const int* __restrict__ pIdx,
                                               const float* __restrict__ xtArr,
                                               float* __restrict__ pNll,
                                               float* __restrict__ pMask,
                                               int* __restrict__ counter,
                                               float* __restrict__ outv) {
    __shared__ float lds[8];
    __shared__ bool isLast;
    int idx = blockIdx.x * 256 + threadIdx.x;            // (b,s) flat

    float sum = 0.f, best = -1e30f;
    int bestIdx = 0;
    #pragma unroll
    for (int c = 0; c < NCHUNK; ++c) {                   // ascending: first-idx ties
        int o = c * NBS + idx;
        sum += pSum[o];
        float sc = pBest[o];
        int ii = pIdx[o];
        if (sc > best) { best = sc; bestIdx = ii; }
    }
    int tgt = target[idx];
    float nll = __logf(sum) - xtArr[idx];

    int pt = ttype[bestIdx], tt = ttype[tgt];
    float pv = tval[bestIdx], tv = tval[tgt];
    float d = fabsf(pv - tv);
    float pw = (d == 7.f) ? harm[0] : (d == 5.f) ? harm[1] : (d == 3.f) ? harm[2]
             : (d == 4.f) ? harm[3] : (d == 1.f) ? harm[4] : (d == 2.f) ? harm[5]
             : harm[6];
    float w = (pt == 0) ? pw
            : (pt == 1) ? coeff[1] * d * (1.f / 160.f)
            : (pt == 2) ? coeff[2] * d * (1.f / 100.f)
            :             coeff[3] * d * (1.f / 128.f);
    float mask = (pt != tt) ? coeff[0] : w;

    int lane = threadIdx.x & 63, wvv = threadIdx.x >> 6;
    float rn = waveReduceSum(nll);
    if (lane == 0) lds[wvv] = rn;
    __syncthreads();
    float totN = (threadIdx.x == 0) ? lds[0] + lds[1] + lds[2] + lds[3] : 0.f;
    __syncthreads();
    float rm = waveReduceSum(mask);
    if (lane == 0) lds[wvv] = rm;
    __syncthreads();
    if (threadIdx.x == 0) {
        pNll[blockIdx.x]  = totN;
        pMask[blockIdx.x] = lds[0] + lds[1] + lds[2] + lds[3];
        __threadfence();
        unsigned old = atomicAdd((unsigned*)counter, 1u);
        isLast = (old == NPART - 1);
    }
    __syncthreads();
    if (isLast) {
        __threadfence();
        int t = threadIdx.x;
        float n = waveReduceSum(pNll[t]);
        float m = waveReduceSum(pMask[t]);
        if (lane == 0) { lds[wvv] = n; lds[4 + wvv] = m; }
        __syncthreads();
        if (t == 0) {
            float tn = lds[0] + lds[1] + lds[2] + lds[3];
            float tm = lds[4] + lds[5] + lds[6] + lds[7];
            const float inv = 1.f / (float)NBS;
            outv[0] = (tn * inv) * (1.f + tm * inv);
        }
    }
}

extern "C" void kernel_launch(void* const* d_in, const int* in_sizes, int n_in,
                              void* d_out, int out_size, void* d_ws, size_t ws_size,
                              hipStream_t stream) {
    const float* x      = (const float*)d_in[0];
    const int*   target = (const int*)d_in[1];
    const int*   ttype  = (const int*)d_in[2];
    const float* tval   = (const float*)d_in[3];
    const float* coeff  = (const float*)d_in[4];
    const float* harm   = (const float*)d_in[5];

    float* ws    = (float*)d_ws;
    int*   ctr   = (int*)ws;                     // 4 ints
    float* pNll  = ws + 4;                       // 256
    float* pMask = pNll + NPART;                 // 256
    float* xtArr = pMask + NPART;                // 65536 (offset 516 -> 16B-aligned)
    float* pSum  = xtArr + NBS;                  // 16*65536
    float* pBest = pSum + (size_t)NCHUNK * NBS;  // 16*65536
    int*   pIdx  = (int*)(pBest + (size_t)NCHUNK * NBS);

    hl_tile<<<BB * NCHUNK, 512, 0, stream>>>(x, target, ctr, pSum, pBest,
                                             pIdx, xtArr);
    hl_comb<<<NBS / 256, 256, 0, stream>>>(target, ttype, tval, coeff, harm,
                                           pSum, pBest, pIdx, xtArr,
                                           pNll, pMask, ctr, (float*)d_out);
}

// Round 12
// 50.430 us; speedup vs baseline: 2.8928x; 1.0493x over previous
//
#include <hip/hip_runtime.h>
#include <hip/hip_fp16.h>

#define BB 32
#define SS 2048
#define VV 516
#define NBS (BB * SS)      // 65536
#define NCHUNK 16
#define NPART 256          // comb block count

struct alignas(8) h4 { __half2 a, b; };

__device__ __forceinline__ float waveReduceSum(float v) {
    #pragma unroll
    for (int o = 32; o > 0; o >>= 1) v += __shfl_down(v, o, 64);
    return v;
}

// One block per (b, v-chunk), 512 threads (8 waves).  Single HBM sweep.
// R7 structure (fastest so far) with the spill removed:
//   - wave wv owns ONE full row per 8-row sub-chunk (8 float4 = 32 regs;
//     double-buffered vbA/vbB = 64 regs; named arrays + constant indices)
//   - __launch_bounds__(512,2): 128-VGPR cap (R10-verified), demand ~105
//   - per sub-chunk k: issue prefetch(k+1) -> finish(k): exp -> fp16 ->
//     ldsE[k&1] + 6-shfl row sum -> sRcp; lgkmcnt(0)+raw s_barrier (global
//     prefetch NOT drained); phase2(k): 8 h4 LDS reads + broadcast rcp;
//     accumulate sum_v e, argmax of e*rcp (== softmax_S value); target
//     logit gathered from LDS as log(e).
// Buffer parity => one barrier per sub-chunk is race-free: finish(k+2)
// rewrites ldsE[k&1] only after barrier(k+1), which every wave reaches only
// after completing phase2(k).
__global__ __launch_bounds__(512, 2) void hl_tile(const float* __restrict__ x,
                                                  const int* __restrict__ target,
                                                  int* __restrict__ ctr,
                                                  float* __restrict__ pSum,
                                                  float* __restrict__ pBest,
                                                  int* __restrict__ pIdx,
                                                  float* __restrict__ xtArr) {
    __shared__ __half ldsE[2][8][2048];   // 64 KB
    __shared__ float  sRcp[2][8];

    if (blockIdx.x == 0 && threadIdx.x == 0) ctr[0] = 0;   // comb finalize ctr

    const int c = blockIdx.x & 15, b = blockIdx.x >> 4;
    const int v0 = 32 * c + (c > 12 ? c - 12 : 0);          // 12x32 + 4x33
    const int nv = (c >= 12) ? 33 : 32;
    const int tid = threadIdx.x, lane = tid & 63, wv = tid >> 6;
    const int s0 = tid << 2;
    const int bs = b * SS + s0;

    int4 tg4 = *(const int4*)(target + bs);
    int tg[4] = {tg4.x, tg4.y, tg4.z, tg4.w};

    float sum[4]  = {0.f, 0.f, 0.f, 0.f};
    float best[4] = {-1.f, -1.f, -1.f, -1.f};
    float xt[4]   = {0.f, 0.f, 0.f, 0.f};
    int   bi[4]   = {v0, v0, v0, v0};

    const float* rowbase = x + (size_t)(b * VV + v0) * SS + lane * 4;

    float4 vbA[8], vbB[8];
    {   // prologue: sub-chunk 0, wave wv owns row wv
        const float* rp = rowbase + (size_t)wv * SS;
        #pragma unroll
        for (int j = 0; j < 8; ++j)
            vbA[j] = *(const float4*)(rp + j * 256);
    }

#define ACC_ROW(HV, RC, VG)                                                   \
    {                                                                         \
        float rc = (RC);                                                      \
        int vg = (VG);                                                        \
        float e0 = __low2float((HV).a), e1 = __high2float((HV).a);            \
        float e2 = __low2float((HV).b), e3 = __high2float((HV).b);            \
        sum[0] += e0; sum[1] += e1; sum[2] += e2; sum[3] += e3;               \
        float c0 = e0*rc, c1 = e1*rc, c2 = e2*rc, c3 = e3*rc;                 \
        if (c0 > best[0]) { best[0] = c0; bi[0] = vg; }                       \
        if (c1 > best[1]) { best[1] = c1; bi[1] = vg; }                       \
        if (c2 > best[2]) { best[2] = c2; bi[2] = vg; }                       \
        if (c3 > best[3]) { best[3] = c3; bi[3] = vg; }                       \
    }

#define TILE_BODY(CUR, NXT, KK)                                               \
    {                                                                         \
        if ((KK) + 1 < 4) {                                                   \
            const float* rp = rowbase + (size_t)(((KK)+1)*8 + wv) * SS;       \
            _Pragma("unroll")                                                 \
            for (int j = 0; j < 8; ++j)                                       \
                NXT[j] = *(const float4*)(rp + j * 256);                      \
        } else if (nv == 33 && wv == 0) {   /* prefetch tail row 32 */        \
            const float* rp = rowbase + (size_t)32 * SS;                      \
            _Pragma("unroll")                                                 \
            for (int j = 0; j < 8; ++j)                                       \
                NXT[j] = *(const float4*)(rp + j * 256);                      \
        }                                                                     \
        {   /* finish(KK): exp, fp16 pack, LDS write, row sum */              \
            __half* dst = &ldsE[(KK)&1][wv][lane * 4];                        \
            float a0 = 0.f, a1 = 0.f, a2 = 0.f, a3 = 0.f;                     \
            _Pragma("unroll")                                                 \
            for (int j = 0; j < 8; ++j) {                                     \
                float ex = __expf(CUR[j].x), ey = __expf(CUR[j].y);           \
                float ez = __expf(CUR[j].z), ew = __expf(CUR[j].w);           \
                h4 h;                                                         \
                h.a = __halves2half2(__float2half_rn(ex), __float2half_rn(ey));\
                h.b = __halves2half2(__float2half_rn(ez), __float2half_rn(ew));\
                *(h4*)(dst + j * 256) = h;                                    \
                a0 += ex; a1 += ey; a2 += ez; a3 += ew;                       \
            }                                                                 \
            float rs = waveReduceSum((a0 + a1) + (a2 + a3));                  \
            if (lane == 0) sRcp[(KK)&1][wv] = 1.f / rs;                       \
        }                                                                     \
        asm volatile("s_waitcnt lgkmcnt(0)" ::: "memory");                    \
        __builtin_amdgcn_s_barrier();                                         \
        {   /* phase2(KK): 8 rows from LDS */                                 \
            const __half* src = &ldsE[(KK)&1][0][s0];                         \
            h4 r0 = *(const h4*)(src + 0 * 2048);                             \
            h4 r1 = *(const h4*)(src + 1 * 2048);                             \
            h4 r2 = *(const h4*)(src + 2 * 2048);                             \
            h4 r3 = *(const h4*)(src + 3 * 2048);                             \
            h4 r4 = *(const h4*)(src + 4 * 2048);                             \
            h4 r5 = *(const h4*)(src + 5 * 2048);                             \
            h4 r6 = *(const h4*)(src + 6 * 2048);                             \
            h4 r7 = *(const h4*)(src + 7 * 2048);                             \
            ACC_ROW(r0, sRcp[(KK)&1][0], v0 + (KK)*8 + 0)                     \
            ACC_ROW(r1, sRcp[(KK)&1][1], v0 + (KK)*8 + 1)                     \
            ACC_ROW(r2, sRcp[(KK)&1][2], v0 + (KK)*8 + 2)                     \
            ACC_ROW(r3, sRcp[(KK)&1][3], v0 + (KK)*8 + 3)                     \
            ACC_ROW(r4, sRcp[(KK)&1][4], v0 + (KK)*8 + 4)                     \
            ACC_ROW(r5, sRcp[(KK)&1][5], v0 + (KK)*8 + 5)                     \
            ACC_ROW(r6, sRcp[(KK)&1][6], v0 + (KK)*8 + 6)                     \
            ACC_ROW(r7, sRcp[(KK)&1][7], v0 + (KK)*8 + 7)                     \
            _Pragma("unroll")                                                 \
            for (int i = 0; i < 4; ++i) {                                     \
                int lr = tg[i] - (v0 + (KK)*8);                               \
                if (lr >= 0 && lr < 8)                                        \
                    xt[i] = __logf(__half2float(ldsE[(KK)&1][lr][s0 + i]));   \
            }                                                                 \
        }                                                                     \
    }

    TILE_BODY(vbA, vbB, 0)
    TILE_BODY(vbB, vbA, 1)
    TILE_BODY(vbA, vbB, 2)
    TILE_BODY(vbB, vbA, 3)
#undef TILE_BODY

    if (nv == 33) {   // tail row 32 (prefetched into vbA by body 3, wave 0)
        if (wv == 0) {
            __half* dst = &ldsE[0][0][lane * 4];
            float a0 = 0.f, a1 = 0.f, a2 = 0.f, a3 = 0.f;
            #pragma unroll
            for (int j = 0; j < 8; ++j) {
                float ex = __expf(vbA[j].x), ey = __expf(vbA[j].y);
                float ez = __expf(vbA[j].z), ew = __expf(vbA[j].w);
                h4 h;
                h.a = __halves2half2(__float2half_rn(ex), __float2half_rn(ey));
                h.b = __halves2half2(__float2half_rn(ez), __float2half_rn(ew));
                *(h4*)(dst + j * 256) = h;
                a0 += ex; a1 += ey; a2 += ez; a3 += ew;
            }
            float rs = waveReduceSum((a0 + a1) + (a2 + a3));
            if (lane == 0) sRcp[0][0] = 1.f / rs;
        }
        asm volatile("s_waitcnt lgkmcnt(0)" ::: "memory");
        __builtin_amdgcn_s_barrier();
        h4 hv = *(const h4*)&ldsE[0][0][s0];
        ACC_ROW(hv, sRcp[0][0], v0 + 32)
        #pragma unroll
        for (int i = 0; i < 4; ++i)
            if (tg[i] == v0 + 32)
                xt[i] = __logf(__half2float(ldsE[0][0][s0 + i]));
    }
#undef ACC_ROW

    // ---- write per-chunk partials ----
    int o = c * NBS + bs;
    *(float4*)(pSum + o)  = make_float4(sum[0], sum[1], sum[2], sum[3]);
    *(float4*)(pBest + o) = make_float4(best[0], best[1], best[2], best[3]);
    *(int4*)(pIdx + o)    = make_int4(bi[0], bi[1], bi[2], bi[3]);
    int v1 = v0 + nv;
    #pragma unroll
    for (int i = 0; i < 4; ++i)
        if (tg[i] >= v0 && tg[i] < v1) xtArr[bs + i] = xt[i];
}

// Merge chunk partials per (b,s); nll + penalty mask; block partial sums;
// last block folds the 256 partials into the scalar output.  (R3-proven.)
__global__ __launch_bounds__(256) void hl_comb(const int* __restrict__ target,
                                               const int* __restrict__ ttype,
                                               const float* __restrict__ tval,
                                               const float* __restrict__ coeff,
                                               const float* __restrict__ harm,
                                               const float* __restrict__ pSum,
                                               const float* __restrict__ pBest,
                                               const int* __restrict__ pIdx,
                                               const float* __restrict__ xtArr,
                                               float* __restrict__ pNll,
                                               float* __restrict__ pMask,
                                               int* __restrict__ counter,
                                               float* __restrict__ outv) {
    __shared__ float lds[8];
    __shared__ bool isLast;
    int idx = blockIdx.x * 256 + threadIdx.x;            // (b,s) flat

    float sum = 0.f, best = -1e30f;
    int bestIdx = 0;
    #pragma unroll
    for (int c = 0; c < NCHUNK; ++c) {                   // ascending: first-idx ties
        int o = c * NBS + idx;
        sum += pSum[o];
        float sc = pBest[o];
        int ii = pIdx[o];
        if (sc > best) { best = sc; bestIdx = ii; }
    }
    int tgt = target[idx];
    float nll = __logf(sum) - xtArr[idx];

    int pt = ttype[bestIdx], tt = ttype[tgt];
    float pv = tval[bestIdx], tv = tval[tgt];
    float d = fabsf(pv - tv);
    float pw = (d == 7.f) ? harm[0] : (d == 5.f) ? harm[1] : (d == 3.f) ? harm[2]
             : (d == 4.f) ? harm[3] : (d == 1.f) ? harm[4] : (d == 2.f) ? harm[5]
             : harm[6];
    float w = (pt == 0) ? pw
            : (pt == 1) ? coeff[1] * d * (1.f / 160.f)
            : (pt == 2) ? coeff[2] * d * (1.f / 100.f)
            :             coeff[3] * d * (1.f / 128.f);
    float mask = (pt != tt) ? coeff[0] : w;

    int lane = threadIdx.x & 63, wvv = threadIdx.x >> 6;
    float rn = waveReduceSum(nll);
    if (lane == 0) lds[wvv] = rn;
    __syncthreads();
    float totN = (threadIdx.x == 0) ? lds[0] + lds[1] + lds[2] + lds[3] : 0.f;
    __syncthreads();
    float rm = waveReduceSum(mask);
    if (lane == 0) lds[wvv] = rm;
    __syncthreads();
    if (threadIdx.x == 0) {
        pNll[blockIdx.x]  = totN;
        pMask[blockIdx.x] = lds[0] + lds[1] + lds[2] + lds[3];
        __threadfence();
        unsigned old = atomicAdd((unsigned*)counter, 1u);
        isLast = (old == NPART - 1);
    }
    __syncthreads();
    if (isLast) {
        __threadfence();
        int t = threadIdx.x;
        float n = waveReduceSum(pNll[t]);
        float m = waveReduceSum(pMask[t]);
        if (lane == 0) { lds[wvv] = n; lds[4 + wvv] = m; }
        __syncthreads();
        if (t == 0) {
            float tn = lds[0] + lds[1] + lds[2] + lds[3];
            float tm = lds[4] + lds[5] + lds[6] + lds[7];
            const float inv = 1.f / (float)NBS;
            outv[0] = (tn * inv) * (1.f + tm * inv);
        }
    }
}

extern "C" void kernel_launch(void* const* d_in, const int* in_sizes, int n_in,
                              void* d_out, int out_size, void* d_ws, size_t ws_size,
                              hipStream_t stream) {
    const float* x      = (const float*)d_in[0];
    const int*   target = (const int*)d_in[1];
    const int*   ttype  = (const int*)d_in[2];
    const float* tval   = (const float*)d_in[3];
    const float* coeff  = (const float*)d_in[4];
    const float* harm   = (const float*)d_in[5];

    float* ws    = (float*)d_ws;
    int*   ctr   = (int*)ws;                     // 4 ints
    float* pNll  = ws + 4;                       // 256
    float* pMask = pNll + NPART;                 // 256
    float* xtArr = pMask + NPART;                // 65536 (offset 516 -> 16B-aligned)
    float* pSum  = xtArr + NBS;                  // 16*65536
    float* pBest = pSum + (size_t)NCHUNK * NBS;  // 16*65536
    int*   pIdx  = (int*)(pBest + (size_t)NCHUNK * NBS);

    hl_tile<<<BB * NCHUNK, 512, 0, stream>>>(x, target, ctr, pSum, pBest,
                                             pIdx, xtArr);
    hl_comb<<<NBS / 256, 256, 0, stream>>>(target, ttype, tval, coeff, harm,
                                           pSum, pBest, pIdx, xtArr,
                                           pNll, pMask, ctr, (float*)d_out);
}

// Round 13
// 47.267 us; speedup vs baseline: 3.0863x; 1.0669x over previous
//
#include <hip/hip_runtime.h>

#define BB 32
#define SS 2048
#define VV 516
#define NBS (BB * SS)      // 65536
#define NCHUNK 16
#define NPART 256          // comb block count

__device__ __forceinline__ float waveReduceSum(float v) {
    #pragma unroll
    for (int o = 32; o > 0; o >>= 1) v += __shfl_down(v, o, 64);
    return v;
}

// Async global -> LDS DMA, 16 bytes per lane (lane l lands at l*16 past the
// wave-uniform LDS base).  No VGPR staging, and WE own every vmcnt.
__device__ __forceinline__ void stage16(const float* g, float* l) {
    __builtin_amdgcn_global_load_lds(
        (const __attribute__((address_space(1))) void*)(g),
        (__attribute__((address_space(3))) void*)(l),
        16, 0, 0);
}

// One block per (b, v-chunk), 512 threads (8 waves), 2 blocks/CU (grid 512 =
// all blocks resident).  Single HBM sweep via global_load_lds:
//   per 4-row sub-chunk k (kb = k&1):
//     1. issue stage(k+1) into buf[kb^1]  (4 x 1KB DMA per wave; stays in
//        flight across the WHOLE body -- waited only at step 5)
//     2. rowsum(k): wave (row=wv>>1, half=wv&1) reads its half-row from
//        buf[kb], exps IN PLACE (write e back), lane-sum + 6-shfl ->
//        ldsH[kb][row][half]
//     3. lgkmcnt(0); sched_barrier; s_barrier   (e + ldsH visible)
//     4. score(k): per thread 4 rows x 4 cols from LDS: sum_v e, argmax of
//        e * rcp(rowsum) (monotone-equiv of x - lseS); target logit log(e)
//     5. vmcnt(0); sched_barrier; s_barrier     (stage(k+1) landed)
// Race-free: stage(k+1) writes buf[kb^1] whose last readers finished before
// barrier(k-1, step5); score(k) reads buf[kb] sealed at step 3.
__global__ __launch_bounds__(512, 2) void hl_tile(const float* __restrict__ x,
                                                  const int* __restrict__ target,
                                                  int* __restrict__ ctr,
                                                  float* __restrict__ pSum,
                                                  float* __restrict__ pBest,
                                                  int* __restrict__ pIdx,
                                                  float* __restrict__ xtArr) {
    __shared__ float buf[2][4][2048];   // 64 KB
    __shared__ float ldsH[2][4][2];     // half-row sums
    __shared__ float ldsT[8];           // tail-row wave partials

    if (blockIdx.x == 0 && threadIdx.x == 0) ctr[0] = 0;   // comb finalize ctr

    const int c = blockIdx.x & 15, b = blockIdx.x >> 4;
    const int v0 = 32 * c + (c > 12 ? c - 12 : 0);          // 12x32 + 4x33
    const int nv = (c >= 12) ? 33 : 32;
    const int tid = threadIdx.x, lane = tid & 63, wv = tid >> 6;
    const int row = wv >> 1, half = wv & 1;
    const int s0 = tid << 2;
    const int bs = b * SS + s0;

    int4 tg4 = *(const int4*)(target + bs);
    int tg[4] = {tg4.x, tg4.y, tg4.z, tg4.w};

    float sum[4]  = {0.f, 0.f, 0.f, 0.f};
    float best[4] = {-1.f, -1.f, -1.f, -1.f};
    float xt[4]   = {0.f, 0.f, 0.f, 0.f};
    int   bi[4]   = {v0, v0, v0, v0};

    // per-lane global src for this wave's (row, half) slice of a sub-chunk
    const float* gbase = x + (size_t)(b * VV + v0 + row) * SS + half * 1024 + lane * 4;

    // ---- prologue: stage sub-chunk 0 ----
    {
        float* ls = &buf[0][row][half * 1024];
        #pragma unroll
        for (int j = 0; j < 4; ++j) stage16(gbase + j * 256, ls + j * 256);
    }
    asm volatile("s_waitcnt vmcnt(0)" ::: "memory");
    __builtin_amdgcn_sched_barrier(0);
    __builtin_amdgcn_s_barrier();

    for (int k = 0; k < 8; ++k) {
        const int kb = k & 1;
        // ---- 1. stage(k+1) ----
        if (k + 1 < 8) {
            const float* gs = gbase + (size_t)(k + 1) * 4 * SS;
            float* ls = &buf[kb ^ 1][row][half * 1024];
            #pragma unroll
            for (int j = 0; j < 4; ++j) stage16(gs + j * 256, ls + j * 256);
        }
        // ---- 2. rowsum(k): exp in place + half-row reduce ----
        {
            float* p = &buf[kb][row][half * 1024 + lane * 4];
            float a = 0.f;
            #pragma unroll
            for (int j = 0; j < 4; ++j) {
                float4 v = *(const float4*)(p + j * 256);
                float4 e;
                e.x = __expf(v.x); e.y = __expf(v.y);
                e.z = __expf(v.z); e.w = __expf(v.w);
                *(float4*)(p + j * 256) = e;
                a += (e.x + e.y) + (e.z + e.w);
            }
            a = waveReduceSum(a);
            if (lane == 0) ldsH[kb][row][half] = a;
        }
        // ---- 3. seal buf[kb] + ldsH (global DMA NOT drained) ----
        asm volatile("s_waitcnt lgkmcnt(0)" ::: "memory");
        __builtin_amdgcn_sched_barrier(0);
        __builtin_amdgcn_s_barrier();
        // ---- 4. score(k) ----
        #pragma unroll
        for (int r = 0; r < 4; ++r) {
            float rs = ldsH[kb][r][0] + ldsH[kb][r][1];
            float rc = 1.f / rs;
            int vg = v0 + k * 4 + r;
            float4 e = *(const float4*)&buf[kb][r][s0];
            sum[0] += e.x; sum[1] += e.y; sum[2] += e.z; sum[3] += e.w;
            float c0 = e.x * rc, c1 = e.y * rc, c2 = e.z * rc, c3 = e.w * rc;
            if (c0 > best[0]) { best[0] = c0; bi[0] = vg; }
            if (c1 > best[1]) { best[1] = c1; bi[1] = vg; }
            if (c2 > best[2]) { best[2] = c2; bi[2] = vg; }
            if (c3 > best[3]) { best[3] = c3; bi[3] = vg; }
        }
        #pragma unroll
        for (int i = 0; i < 4; ++i) {
            int lr = tg[i] - (v0 + k * 4);
            if (lr >= 0 && lr < 4) xt[i] = __logf(buf[kb][lr][s0 + i]);
        }
        // ---- 5. stage(k+1) landed; recycle buffers ----
        asm volatile("s_waitcnt vmcnt(0)" ::: "memory");
        __builtin_amdgcn_sched_barrier(0);
        __builtin_amdgcn_s_barrier();
    }

    if (nv == 33) {   // tail row 32: plain loads, block-wide rowsum
        int vg = v0 + 32;
        float4 xv = *(const float4*)(x + (size_t)(b * VV + vg) * SS + s0);
        float4 e;
        e.x = __expf(xv.x); e.y = __expf(xv.y);
        e.z = __expf(xv.z); e.w = __expf(xv.w);
        float a = waveReduceSum((e.x + e.y) + (e.z + e.w));
        if (lane == 0) ldsT[wv] = a;
        asm volatile("s_waitcnt lgkmcnt(0)" ::: "memory");
        __builtin_amdgcn_sched_barrier(0);
        __builtin_amdgcn_s_barrier();
        float rs = ((ldsT[0] + ldsT[1]) + (ldsT[2] + ldsT[3]))
                 + ((ldsT[4] + ldsT[5]) + (ldsT[6] + ldsT[7]));
        float rc = 1.f / rs;
        if (vg == tg[0]) xt[0] = xv.x;
        if (vg == tg[1]) xt[1] = xv.y;
        if (vg == tg[2]) xt[2] = xv.z;
        if (vg == tg[3]) xt[3] = xv.w;
        sum[0] += e.x; sum[1] += e.y; sum[2] += e.z; sum[3] += e.w;
        float c0 = e.x * rc, c1 = e.y * rc, c2 = e.z * rc, c3 = e.w * rc;
        if (c0 > best[0]) { best[0] = c0; bi[0] = vg; }
        if (c1 > best[1]) { best[1] = c1; bi[1] = vg; }
        if (c2 > best[2]) { best[2] = c2; bi[2] = vg; }
        if (c3 > best[3]) { best[3] = c3; bi[3] = vg; }
    }

    // ---- write per-chunk partials ----
    int o = c * NBS + bs;
    *(float4*)(pSum + o)  = make_float4(sum[0], sum[1], sum[2], sum[3]);
    *(float4*)(pBest + o) = make_float4(best[0], best[1], best[2], best[3]);
    *(int4*)(pIdx + o)    = make_int4(bi[0], bi[1], bi[2], bi[3]);
    int v1 = v0 + nv;
    #pragma unroll
    for (int i = 0; i < 4; ++i)
        if (tg[i] >= v0 && tg[i] < v1) xtArr[bs + i] = xt[i];
}

// Merge chunk partials per (b,s); nll + penalty mask; block partial sums;
// last block folds the 256 partials into the scalar output.  (R3-proven.)
__global__ __launch_bounds__(256) void hl_comb(const int* __restrict__ target,
                                               const int* __restrict__ ttype,
                                               const float* __restrict__ tval,
                                               const float* __restrict__ coeff,
                                               const float* __restrict__ harm,
                                               const float* __restrict__ pSum,
                                               const float* __restrict__ pBest,
                                               const int* __restrict__ pIdx,
                                               const float* __restrict__ xtArr,
                                               float* __restrict__ pNll,
                                               float* __restrict__ pMask,
                                               int* __restrict__ counter,
                                               float* __restrict__ outv) {
    __shared__ float lds[8];
    __shared__ bool isLast;
    int idx = blockIdx.x * 256 + threadIdx.x;            // (b,s) flat

    float sum = 0.f, best = -1e30f;
    int bestIdx = 0;
    #pragma unroll
    for (int c = 0; c < NCHUNK; ++c) {                   // ascending: first-idx ties
        int o = c * NBS + idx;
        sum += pSum[o];
        float sc = pBest[o];
        int ii = pIdx[o];
        if (sc > best) { best = sc; bestIdx = ii; }
    }
    int tgt = target[idx];
    float nll = __logf(sum) - xtArr[idx];

    int pt = ttype[bestIdx], tt = ttype[tgt];
    float pv = tval[bestIdx], tv = tval[tgt];
    float d = fabsf(pv - tv);
    float pw = (d == 7.f) ? harm[0] : (d == 5.f) ? harm[1] : (d == 3.f) ? harm[2]
             : (d == 4.f) ? harm[3] : (d == 1.f) ? harm[4] : (d == 2.f) ? harm[5]
             : harm[6];
    float w = (pt == 0) ? pw
            : (pt == 1) ? coeff[1] * d * (1.f / 160.f)
            : (pt == 2) ? coeff[2] * d * (1.f / 100.f)
            :             coeff[3] * d * (1.f / 128.f);
    float mask = (pt != tt) ? coeff[0] : w;

    int lane = threadIdx.x & 63, wvv = threadIdx.x >> 6;
    float rn = waveReduceSum(nll);
    if (lane == 0) lds[wvv] = rn;
    __syncthreads();
    float totN = (threadIdx.x == 0) ? lds[0] + lds[1] + lds[2] + lds[3] : 0.f;
    __syncthreads();
    float rm = waveReduceSum(mask);
    if (lane == 0) lds[wvv] = rm;
    __syncthreads();
    if (threadIdx.x == 0) {
        pNll[blockIdx.x]  = totN;
        pMask[blockIdx.x] = lds[0] + lds[1] + lds[2] + lds[3];
        __threadfence();
        unsigned old = atomicAdd((unsigned*)counter, 1u);
        isLast = (old == NPART - 1);
    }
    __syncthreads();
    if (isLast) {
        __threadfence();
        int t = threadIdx.x;
        float n = waveReduceSum(pNll[t]);
        float m = waveReduceSum(pMask[t]);
        if (lane == 0) { lds[wvv] = n; lds[4 + wvv] = m; }
        __syncthreads();
        if (t == 0) {
            float tn = lds[0] + lds[1] + lds[2] + lds[3];
            float tm = lds[4] + lds[5] + lds[6] + lds[7];
            const float inv = 1.f / (float)NBS;
            outv[0] = (tn * inv) * (1.f + tm * inv);
        }
    }
}

extern "C" void kernel_launch(void* const* d_in, const int* in_sizes, int n_in,
                              void* d_out, int out_size, void* d_ws, size_t ws_size,
                              hipStream_t stream) {
    const float* x      = (const float*)d_in[0];
    const int*   target = (const int*)d_in[1];
    const int*   ttype  = (const int*)d_in[2];
    const float* tval   = (const float*)d_in[3];
    const float* coeff  = (const float*)d_in[4];
    const float* harm   = (const float*)d_in[5];

    float* ws    = (float*)d_ws;
    int*   ctr   = (int*)ws;                     // 4 ints
    float* pNll  = ws + 4;                       // 256
    float* pMask = pNll + NPART;                 // 256
    float* xtArr = pMask + NPART;                // 65536 (offset 516 -> 16B-aligned)
    float* pSum  = xtArr + NBS;                  // 16*65536
    float* pBest = pSum + (size_t)NCHUNK * NBS;  // 16*65536
    int*   pIdx  = (int*)(pBest + (size_t)NCHUNK * NBS);

    hl_tile<<<BB * NCHUNK, 512, 0, stream>>>(x, target, ctr, pSum, pBest,
                                             pIdx, xtArr);
    hl_comb<<<NBS / 256, 256, 0, stream>>>(target, ttype, tval, coeff, harm,
                                           pSum, pBest, pIdx, xtArr,
                                           pNll, pMask, ctr, (float*)d_out);
}